// Round 3
// baseline (123.691 us; speedup 1.0000x reference)
//
#include <hip/hip_runtime.h>
#include <math.h>

// Workspace float offsets (ws)
#define FVC_OFF   0          // 128 * 1024
#define PHIQ_OFF  131072     // 128 * 1024
#define PHIK_OFF  262144     // 128 * 1024
// G scratch lives in d_out[0 .. 1048576) — consumed by modes_kernel before
// dist_mix_inv_kernel overwrites the whole output. Stream order makes this safe.
#define OUT_KX_OFF 4194304   // kx location in d_out (after 4*32*256*128 floats)

#define TWOPI_128 0.049087385212340517f

// ---------------------------------------------------------------------------
// K1a: row DFT (w -> v modes), radix-4 split. One block = 16 rows of 1 image.
// grid 2048 = 256 images * 8 row-chunks (8 blocks/CU). Writes G[img][v][h].
// ---------------------------------------------------------------------------
__global__ __launch_bounds__(256) void dft_rows_kernel(
    const float* __restrict__ z, float* __restrict__ Gout)
{
    __shared__ float ct[128], st[128];
    __shared__ float rows[16 * 132];
    __shared__ float2 tile[16 * 17];

    const int tid = threadIdx.x;
    const int img = blockIdx.x >> 3;
    const int c0  = blockIdx.x & 7;
    const int bt  = img & 127;
    const int isY = img >> 7;

    if (tid < 128) {
        float s, c;
        sincosf((float)tid * TWOPI_128, &s, &c);
        ct[tid] = c; st[tid] = s;
    }
    const float* xim = z + (size_t)bt * 32768 + (size_t)isY * 16384 + (size_t)c0 * 2048;
    {
        int q0 = tid, q1 = tid + 256;
        float4 a = *(const float4*)(xim + (q0 >> 5) * 128 + (q0 & 31) * 4);
        float4 b = *(const float4*)(xim + (q1 >> 5) * 128 + (q1 & 31) * 4);
        *(float4*)(rows + (q0 >> 5) * 132 + (q0 & 31) * 4) = a;
        *(float4*)(rows + (q1 >> 5) * 132 + (q1 & 31) * 4) = b;
    }
    __syncthreads();

    const int v  = tid & 15;
    const int hl = tid >> 4;
    float sr0 = 0.f, si0 = 0.f, sr1 = 0.f, si1 = 0.f;
    float sr2 = 0.f, si2 = 0.f, sr3 = 0.f, si3 = 0.f;
    const float4* rp = (const float4*)(rows + hl * 132);
    #pragma unroll 8
    for (int m = 0; m < 32; ++m) {
        float4 x4 = rp[m];
        int k = (v * m * 4) & 127;
        float c = ct[k], s = st[k];
        sr0 = fmaf(x4.x, c, sr0); si0 = fmaf(x4.x, s, si0);
        sr1 = fmaf(x4.y, c, sr1); si1 = fmaf(x4.y, s, si1);
        sr2 = fmaf(x4.z, c, sr2); si2 = fmaf(x4.z, s, si2);
        sr3 = fmaf(x4.w, c, sr3); si3 = fmaf(x4.w, s, si3);
    }
    float c1 = ct[v], s1 = st[v];
    float c2 = ct[(2 * v) & 127], s2 = st[(2 * v) & 127];
    float c3 = ct[(3 * v) & 127], s3 = st[(3 * v) & 127];
    float gr = sr0 + sr1 * c1 - si1 * s1 + sr2 * c2 - si2 * s2 + sr3 * c3 - si3 * s3;
    float gi = -(si0 + sr1 * s1 + si1 * c1 + sr2 * s2 + si2 * c2 + sr3 * s3 + si3 * c3);

    tile[v * 17 + hl] = make_float2(gr, gi);
    __syncthreads();
    const int vw = tid >> 4, hw = tid & 15;
    float2 val = tile[vw * 17 + hw];
    *(float2*)(Gout + (size_t)img * 4096 + vw * 256 + (c0 * 16 + hw) * 2) = val;
}

// ---------------------------------------------------------------------------
// K1b: column DFT (h -> u in {0..15,112..127}) + weights/phi/conv.
// grid 1024 = 256 images * 4 v-groups (4 blocks/CU); block 128 = 32 u * 4 v.
// ---------------------------------------------------------------------------
__global__ __launch_bounds__(128) void modes_kernel(
    const float* __restrict__ Gglob,
    const float* __restrict__ qw1r, const float* __restrict__ qw1i,
    const float* __restrict__ qw2r, const float* __restrict__ qw2i,
    const float* __restrict__ kw1r, const float* __restrict__ kw1i,
    const float* __restrict__ kw2r, const float* __restrict__ kw2i,
    const float* __restrict__ icl,  const float* __restrict__ ker,
    float* __restrict__ ws)
{
    __shared__ float ct[128], st[128];
    __shared__ float Gbuf[4 * 260];
    __shared__ float f0r[64], f0i[64];

    const int tid = threadIdx.x;
    const int img = blockIdx.x >> 2;
    const int vg  = blockIdx.x & 3;
    const int bt  = img & 127;
    const int isY = img >> 7;

    {
        float s, c;
        sincosf((float)tid * TWOPI_128, &s, &c);
        ct[tid] = c; st[tid] = s;
    }
    const float4* gsrc = (const float4*)(Gglob + (size_t)img * 4096 + (size_t)vg * 1024);
    {
        float4 a = gsrc[tid];
        float4 b = gsrc[tid + 128];
        *(float4*)(Gbuf + (tid >> 6) * 260 + (tid & 63) * 4) = a;
        *(float4*)(Gbuf + ((tid >> 6) + 2) * 260 + (tid & 63) * 4) = b;
    }
    __syncthreads();

    const int uu = tid & 31;        // slot index 0..31
    const int vl = tid >> 5;        // 0..3
    const int v  = vg * 4 + vl;
    const int u  = (uu < 16) ? uu : uu + 96;   // actual u

    float sr[4] = {0.f, 0.f, 0.f, 0.f}, si[4] = {0.f, 0.f, 0.f, 0.f};
    const float4* gp = (const float4*)(Gbuf + vl * 260);
    #pragma unroll 8
    for (int m = 0; m < 32; ++m) {
        float4 ga = gp[2 * m];       // h=4m, 4m+1 (re,im,re,im)
        float4 gb = gp[2 * m + 1];   // h=4m+2, 4m+3
        int k0 = (u * 4 * m) & 127;
        float c0 = ct[k0], s0 = st[k0];
        sr[0] = fmaf(ga.x, c0, fmaf(ga.y,  s0, sr[0]));
        si[0] = fmaf(ga.y, c0, fmaf(-ga.x, s0, si[0]));
        sr[1] = fmaf(ga.z, c0, fmaf(ga.w,  s0, sr[1]));
        si[1] = fmaf(ga.w, c0, fmaf(-ga.z, s0, si[1]));
        sr[2] = fmaf(gb.x, c0, fmaf(gb.y,  s0, sr[2]));
        si[2] = fmaf(gb.y, c0, fmaf(-gb.x, s0, si[2]));
        sr[3] = fmaf(gb.z, c0, fmaf(gb.w,  s0, sr[3]));
        si[3] = fmaf(gb.w, c0, fmaf(-gb.z, s0, si[3]));
    }
    float mr = sr[0], mi_ = si[0];
    #pragma unroll
    for (int j = 1; j < 4; ++j) {
        int k = (u * j) & 127;
        float cb = ct[k], sb = st[k];
        mr  += sr[j] * cb + si[j] * sb;
        mi_ += si[j] * cb - sr[j] * sb;
    }

    const int wi = (uu & 15) * 16 + v;

    if (!isY) {
        float a, bi_;
        if (uu < 16) { a = qw1r[wi]; bi_ = qw1i[wi]; }
        else         { a = qw2r[wi]; bi_ = qw2i[wi]; }
        float fqr = mr * a - mi_ * bi_;
        float fqi = mr * bi_ + mi_ * a;
        if (uu < 16) { a = kw1r[wi]; bi_ = kw1i[wi]; }
        else         { a = kw2r[wi]; bi_ = kw2i[wi]; }
        float fkr = mr * a - mi_ * bi_;
        float fki = mr * bi_ + mi_ * a;

        float* PQ = ws + PHIQ_OFF + (size_t)bt * 1024;
        float* PK = ws + PHIK_OFF + (size_t)bt * 1024;
        const float c2 = 0.011048543456039806f;  // sqrt(2)/128
        if (v >= 1) {
            int o = ((v - 1) * 32 + uu) * 2;
            PQ[o] = c2 * fqr; PQ[o + 1] = c2 * fqi;
            PK[o] = c2 * fkr; PK[o + 1] = c2 * fki;
        } else {
            f0r[uu]      = fqr; f0i[uu]      = fqi;
            f0r[32 + uu] = fkr; f0i[32 + uu] = fki;
        }
        __syncthreads();
        if (vg == 0) {
            const float c1n = 0.0078125f;        // 1/128
            if (tid == 0) {
                PQ[960] = c1n * f0r[0];
                PK[960] = c1n * f0r[32];
            } else if (tid <= 15) {
                int uf = tid;
                float hr = 0.5f * (f0r[uf] + f0r[32 - uf]);
                float hi = 0.5f * (f0i[uf] - f0i[32 - uf]);
                int o = 961 + (uf - 1) * 2;
                PQ[o] = c2 * hr; PQ[o + 1] = c2 * hi;
                hr = 0.5f * (f0r[32 + uf] + f0r[32 + (32 - uf)]);
                hi = 0.5f * (f0i[32 + uf] - f0i[32 + (32 - uf)]);
                PK[o] = c2 * hr; PK[o + 1] = c2 * hi;
            } else if (tid == 16) {
                PQ[991] = c2 * 0.5f * f0r[16]; PQ[992] = -c2 * 0.5f * f0i[16];
                PK[991] = c2 * 0.5f * f0r[48]; PK[992] = -c2 * 0.5f * f0i[48];
            } else if (tid < 48) {
                PQ[993 + (tid - 17)] = 0.f;
                PK[993 + (tid - 17)] = 0.f;
            }
        }
    } else {
        float s = icl[0];
        float khr = 0.f, khi = 0.f;
        #pragma unroll
        for (int a2 = 0; a2 < 5; ++a2) {
            #pragma unroll
            for (int c3 = 0; c3 < 5; ++c3) {
                float kv = ker[a2 * 5 + c3];
                int e = (u * (a2 - 2) + v * (c3 - 2)) & 127;
                khr = fmaf(kv, ct[e], khr);
                khi = fmaf(kv, st[e], khi);
            }
        }
        const int slot = uu * 16 + v;
        float* FV = ws + FVC_OFF + (size_t)bt * 1024;
        FV[slot * 2]     = s * (mr * khr - mi_ * khi);
        FV[slot * 2 + 1] = s * (mr * khi + mi_ * khr);
    }
}

// ---------------------------------------------------------------------------
// K2: per-(b,q,quarter): compute kx column (32 dists), mix Fvc, inverse
// transform 32 h-rows, store zeros+attn_y (+ kx column once).
// grid 512 (2 blocks/CU); block 256.
// ---------------------------------------------------------------------------
__global__ __launch_bounds__(256) void dist_mix_inv_kernel(
    const float* __restrict__ ws, float* __restrict__ out)
{
    __shared__ float ct[128], st[128];
    __shared__ float kxs[32];
    __shared__ float fmP[32 * 36];          // padded: slot(u,v) -> u*36 + v*2
    __shared__ float Ar[32 * 17], Ai[32 * 17];

    const int tid     = threadIdx.x;
    const int b       = blockIdx.x >> 7;
    const int rest    = blockIdx.x & 127;
    const int q       = rest >> 2;
    const int quarter = rest & 3;

    if (tid < 128) {
        float s, c;
        sincosf((float)tid * TWOPI_128, &s, &c);
        ct[tid] = c; st[tid] = s;
    }

    // ---- dist: kx[b,t,q] for t=0..31 ----
    {
        const int t = tid >> 3, seg = tid & 7;
        const float4* qp = (const float4*)(ws + PHIQ_OFF + (size_t)(b * 32 + t) * 1024) + seg * 32;
        const float4* kp = (const float4*)(ws + PHIK_OFF + (size_t)(b * 32 + q) * 1024) + seg * 32;
        float acc = 0.f;
        #pragma unroll 8
        for (int d = 0; d < 32; ++d) {
            float4 qv = qp[d], kv = kp[d];
            float d0 = qv.x - kv.x, d1 = qv.y - kv.y;
            float d2 = qv.z - kv.z, d3 = qv.w - kv.w;
            acc = fmaf(d0, d0, acc); acc = fmaf(d1, d1, acc);
            acc = fmaf(d2, d2, acc); acc = fmaf(d3, d3, acc);
        }
        acc += __shfl_xor(acc, 1);
        acc += __shfl_xor(acc, 2);
        acc += __shfl_xor(acc, 4);
        if (seg == 0) {
            float l2  = sqrtf(acc + 1e-8f);
            float kxv = (t == 31) ? 0.f : expf(-l2);
            kxs[t] = kxv;
            if (quarter == 0)
                out[OUT_KX_OFF + (b * 32 + t) * 32 + q] = kxv;
        }
    }
    __syncthreads();

    // ---- mix: fm = sum_t kx[t] * Fvc[b,t] (padded LDS layout) ----
    {
        float4 acc = make_float4(0.f, 0.f, 0.f, 0.f);
        const float4* FV = (const float4*)(ws + FVC_OFF) + (size_t)b * 32 * 256;
        for (int i = 0; i < 31; ++i) {
            float kv = kxs[i];
            float4 f = FV[(size_t)i * 256 + tid];
            acc.x = fmaf(kv, f.x, acc.x);
            acc.y = fmaf(kv, f.y, acc.y);
            acc.z = fmaf(kv, f.z, acc.z);
            acc.w = fmaf(kv, f.w, acc.w);
        }
        int s0 = tid * 2;   // first of two slots covered by this float4
        *(float4*)(fmP + (s0 >> 4) * 36 + (s0 & 15) * 2) = acc;
    }
    __syncthreads();

    // ---- phase 2: A_v(h) for our 32 h rows ----
    {
        const int hl = tid >> 3;
        const int v0 = (tid & 7) * 2;
        const int h  = quarter * 32 + hl;
        float ar0 = 0.f, ai0 = 0.f, ar1 = 0.f, ai1 = 0.f;
        #pragma unroll 4
        for (int ui2 = 0; ui2 < 32; ++ui2) {
            int u = (ui2 < 16) ? ui2 : ui2 + 96;
            int k = (u * h) & 127;
            float cc = ct[k], ss = st[k];
            float4 f = *(const float4*)(fmP + ui2 * 36 + v0 * 2);
            ar0 = fmaf(f.x, cc, fmaf(-f.y, ss, ar0));
            ai0 = fmaf(f.x, ss, fmaf( f.y, cc, ai0));
            ar1 = fmaf(f.z, cc, fmaf(-f.w, ss, ar1));
            ai1 = fmaf(f.z, ss, fmaf( f.w, cc, ai1));
        }
        Ar[hl * 17 + v0]     = ar0; Ai[hl * 17 + v0]     = ai0;
        Ar[hl * 17 + v0 + 1] = ar1; Ai[hl * 17 + v0 + 1] = ai1;
    }
    __syncthreads();

    // ---- phase 3: pixels for our 32 rows ----
    const int w2   = tid & 127;
    const int hpar = tid >> 7;
    float cw[16], sw[16];
    #pragma unroll
    for (int v = 1; v < 16; ++v) {
        int k = (v * w2) & 127;
        cw[v] = ct[k]; sw[v] = st[k];
    }
    const size_t obase = (size_t)(b * 32 + q) * 32768;
    for (int it = 0; it < 16; ++it) {
        int l = it * 2 + hpar;
        int r = quarter * 32 + l;
        const float* arp = Ar + l * 17;
        const float* aip = Ai + l * 17;
        float accp = arp[0];
        #pragma unroll
        for (int v = 1; v < 16; ++v)
            accp += 2.f * (arp[v] * cw[v] - aip[v] * sw[v]);
        out[obase + (size_t)r * 128 + w2] = 0.f;
        out[obase + (size_t)(128 + r) * 128 + w2] = accp * 6.103515625e-05f;
    }
}

extern "C" void kernel_launch(void* const* d_in, const int* in_sizes, int n_in,
                              void* d_out, int out_size, void* d_ws, size_t ws_size,
                              hipStream_t stream)
{
    (void)in_sizes; (void)n_in; (void)out_size; (void)ws_size;
    const float* z    = (const float*)d_in[0];
    const float* qw1r = (const float*)d_in[1];
    const float* qw1i = (const float*)d_in[2];
    const float* qw2r = (const float*)d_in[3];
    const float* qw2i = (const float*)d_in[4];
    const float* kw1r = (const float*)d_in[5];
    const float* kw1i = (const float*)d_in[6];
    const float* kw2r = (const float*)d_in[7];
    const float* kw2i = (const float*)d_in[8];
    const float* icl  = (const float*)d_in[9];
    const float* ker  = (const float*)d_in[10];
    float* ws  = (float*)d_ws;
    float* out = (float*)d_out;

    hipLaunchKernelGGL(dft_rows_kernel, dim3(2048), dim3(256), 0, stream, z, out);
    hipLaunchKernelGGL(modes_kernel, dim3(1024), dim3(128), 0, stream,
                       out, qw1r, qw1i, qw2r, qw2i, kw1r, kw1i, kw2r, kw2i,
                       icl, ker, ws);
    hipLaunchKernelGGL(dist_mix_inv_kernel, dim3(512), dim3(256), 0, stream, ws, out);
}

// Round 4
// 116.335 us; speedup vs baseline: 1.0632x; 1.0632x over previous
//
#include <hip/hip_runtime.h>
#include <math.h>

// Workspace float offsets (ws)
#define FVC_OFF   0          // 128 * 1024
#define PHIQ_OFF  131072     // 128 * 1024
#define PHIK_OFF  262144     // 128 * 1024
// G scratch lives in d_out[0 .. 1048576) — consumed by modes_kernel before
// dist_mix_inv_kernel overwrites the whole output. Stream order makes this safe.
#define OUT_KX_OFF 4194304   // kx location in d_out (after 4*32*256*128 floats)

#define TWOPI_128 0.049087385212340517f
#define OUT_SCALE 6.103515625e-05f   // 1/16384

// ---------------------------------------------------------------------------
// K1a: row DFT (w -> v modes), radix-4 split, register-rotated twiddles.
// grid 2048 = 256 images * 8 row-chunks (8 blocks/CU). Writes G[img][v][h].
// ---------------------------------------------------------------------------
__global__ __launch_bounds__(256) void dft_rows_kernel(
    const float* __restrict__ z, float* __restrict__ Gout)
{
    __shared__ float2 tw[128];
    __shared__ float rows[16 * 132];
    __shared__ float2 tile[16 * 17];

    const int tid = threadIdx.x;
    const int img = blockIdx.x >> 3;
    const int c0  = blockIdx.x & 7;
    const int bt  = img & 127;
    const int isY = img >> 7;

    if (tid < 128) {
        float s, c;
        sincosf((float)tid * TWOPI_128, &s, &c);
        tw[tid] = make_float2(c, s);
    }
    const float* xim = z + (size_t)bt * 32768 + (size_t)isY * 16384 + (size_t)c0 * 2048;
    {
        int q0 = tid, q1 = tid + 256;
        float4 a = *(const float4*)(xim + (q0 >> 5) * 128 + (q0 & 31) * 4);
        float4 b = *(const float4*)(xim + (q1 >> 5) * 128 + (q1 & 31) * 4);
        *(float4*)(rows + (q0 >> 5) * 132 + (q0 & 31) * 4) = a;
        *(float4*)(rows + (q1 >> 5) * 132 + (q1 & 31) * 4) = b;
    }
    __syncthreads();

    const int v  = tid & 15;
    const int hl = tid >> 4;
    const float2 stp = tw[(4 * v) & 127];
    float cc = 1.f, ss = 0.f;
    float sr0 = 0.f, si0 = 0.f, sr1 = 0.f, si1 = 0.f;
    float sr2 = 0.f, si2 = 0.f, sr3 = 0.f, si3 = 0.f;
    const float4* rp = (const float4*)(rows + hl * 132);
    #pragma unroll 8
    for (int m = 0; m < 32; ++m) {
        float4 x4 = rp[m];
        sr0 = fmaf(x4.x, cc, sr0); si0 = fmaf(x4.x, ss, si0);
        sr1 = fmaf(x4.y, cc, sr1); si1 = fmaf(x4.y, ss, si1);
        sr2 = fmaf(x4.z, cc, sr2); si2 = fmaf(x4.z, ss, si2);
        sr3 = fmaf(x4.w, cc, sr3); si3 = fmaf(x4.w, ss, si3);
        float t0 = fmaf(cc, stp.x, -(ss * stp.y));
        float t1 = fmaf(cc, stp.y,  (ss * stp.x));
        cc = t0; ss = t1;
    }
    float2 w1 = tw[v];
    float2 w2 = tw[(2 * v) & 127];
    float2 w3 = tw[(3 * v) & 127];
    float gr = sr0 + sr1 * w1.x - si1 * w1.y + sr2 * w2.x - si2 * w2.y + sr3 * w3.x - si3 * w3.y;
    float gi = -(si0 + sr1 * w1.y + si1 * w1.x + sr2 * w2.y + si2 * w2.x + sr3 * w3.y + si3 * w3.x);

    tile[v * 17 + hl] = make_float2(gr, gi);
    __syncthreads();
    const int vw = tid >> 4, hw = tid & 15;
    float2 val = tile[vw * 17 + hw];
    *(float2*)(Gout + (size_t)img * 4096 + vw * 256 + (c0 * 16 + hw) * 2) = val;
}

// ---------------------------------------------------------------------------
// K1b: column DFT (h -> u in {0..15,112..127}) + weights/phi/conv.
// grid 1024 = 256 images * 4 v-groups; block 128 = 32 u * 4 v. Rotated twiddles.
// ---------------------------------------------------------------------------
__global__ __launch_bounds__(128) void modes_kernel(
    const float* __restrict__ Gglob,
    const float* __restrict__ qw1r, const float* __restrict__ qw1i,
    const float* __restrict__ qw2r, const float* __restrict__ qw2i,
    const float* __restrict__ kw1r, const float* __restrict__ kw1i,
    const float* __restrict__ kw2r, const float* __restrict__ kw2i,
    const float* __restrict__ icl,  const float* __restrict__ ker,
    float* __restrict__ ws)
{
    __shared__ float2 tw[128];
    __shared__ float Gbuf[4 * 260];
    __shared__ float f0r[64], f0i[64];

    const int tid = threadIdx.x;
    const int img = blockIdx.x >> 2;
    const int vg  = blockIdx.x & 3;
    const int bt  = img & 127;
    const int isY = img >> 7;

    {
        float s, c;
        sincosf((float)tid * TWOPI_128, &s, &c);
        tw[tid] = make_float2(c, s);
    }
    const float4* gsrc = (const float4*)(Gglob + (size_t)img * 4096 + (size_t)vg * 1024);
    {
        float4 a = gsrc[tid];
        float4 b = gsrc[tid + 128];
        *(float4*)(Gbuf + (tid >> 6) * 260 + (tid & 63) * 4) = a;
        *(float4*)(Gbuf + ((tid >> 6) + 2) * 260 + (tid & 63) * 4) = b;
    }
    __syncthreads();

    const int uu = tid & 31;
    const int vl = tid >> 5;
    const int v  = vg * 4 + vl;
    const int u  = (uu < 16) ? uu : uu + 96;

    const float2 stp = tw[(4 * u) & 127];
    float cc = 1.f, ss = 0.f;
    float sr[4] = {0.f, 0.f, 0.f, 0.f}, si[4] = {0.f, 0.f, 0.f, 0.f};
    const float4* gp = (const float4*)(Gbuf + vl * 260);
    #pragma unroll 8
    for (int m = 0; m < 32; ++m) {
        float4 ga = gp[2 * m];
        float4 gb = gp[2 * m + 1];
        sr[0] = fmaf(ga.x, cc, fmaf(ga.y,  ss, sr[0]));
        si[0] = fmaf(ga.y, cc, fmaf(-ga.x, ss, si[0]));
        sr[1] = fmaf(ga.z, cc, fmaf(ga.w,  ss, sr[1]));
        si[1] = fmaf(ga.w, cc, fmaf(-ga.z, ss, si[1]));
        sr[2] = fmaf(gb.x, cc, fmaf(gb.y,  ss, sr[2]));
        si[2] = fmaf(gb.y, cc, fmaf(-gb.x, ss, si[2]));
        sr[3] = fmaf(gb.z, cc, fmaf(gb.w,  ss, sr[3]));
        si[3] = fmaf(gb.w, cc, fmaf(-gb.z, ss, si[3]));
        float t0 = fmaf(cc, stp.x, -(ss * stp.y));
        float t1 = fmaf(cc, stp.y,  (ss * stp.x));
        cc = t0; ss = t1;
    }
    float mr = sr[0], mi_ = si[0];
    #pragma unroll
    for (int j = 1; j < 4; ++j) {
        float2 wj = tw[(u * j) & 127];
        mr  += sr[j] * wj.x + si[j] * wj.y;
        mi_ += si[j] * wj.x - sr[j] * wj.y;
    }

    const int wi = (uu & 15) * 16 + v;

    if (!isY) {
        float a, bi_;
        if (uu < 16) { a = qw1r[wi]; bi_ = qw1i[wi]; }
        else         { a = qw2r[wi]; bi_ = qw2i[wi]; }
        float fqr = mr * a - mi_ * bi_;
        float fqi = mr * bi_ + mi_ * a;
        if (uu < 16) { a = kw1r[wi]; bi_ = kw1i[wi]; }
        else         { a = kw2r[wi]; bi_ = kw2i[wi]; }
        float fkr = mr * a - mi_ * bi_;
        float fki = mr * bi_ + mi_ * a;

        float* PQ = ws + PHIQ_OFF + (size_t)bt * 1024;
        float* PK = ws + PHIK_OFF + (size_t)bt * 1024;
        const float c2 = 0.011048543456039806f;  // sqrt(2)/128
        if (v >= 1) {
            int o = ((v - 1) * 32 + uu) * 2;
            PQ[o] = c2 * fqr; PQ[o + 1] = c2 * fqi;
            PK[o] = c2 * fkr; PK[o + 1] = c2 * fki;
        } else {
            f0r[uu]      = fqr; f0i[uu]      = fqi;
            f0r[32 + uu] = fkr; f0i[32 + uu] = fki;
        }
        __syncthreads();
        if (vg == 0) {
            const float c1n = 0.0078125f;        // 1/128
            if (tid == 0) {
                PQ[960] = c1n * f0r[0];
                PK[960] = c1n * f0r[32];
            } else if (tid <= 15) {
                int uf = tid;
                float hr = 0.5f * (f0r[uf] + f0r[32 - uf]);
                float hi = 0.5f * (f0i[uf] - f0i[32 - uf]);
                int o = 961 + (uf - 1) * 2;
                PQ[o] = c2 * hr; PQ[o + 1] = c2 * hi;
                hr = 0.5f * (f0r[32 + uf] + f0r[32 + (32 - uf)]);
                hi = 0.5f * (f0i[32 + uf] - f0i[32 + (32 - uf)]);
                PK[o] = c2 * hr; PK[o + 1] = c2 * hi;
            } else if (tid == 16) {
                PQ[991] = c2 * 0.5f * f0r[16]; PQ[992] = -c2 * 0.5f * f0i[16];
                PK[991] = c2 * 0.5f * f0r[48]; PK[992] = -c2 * 0.5f * f0i[48];
            } else if (tid < 48) {
                PQ[993 + (tid - 17)] = 0.f;
                PK[993 + (tid - 17)] = 0.f;
            }
        }
    } else {
        float s = icl[0];
        float khr = 0.f, khi = 0.f;
        #pragma unroll
        for (int a2 = 0; a2 < 5; ++a2) {
            #pragma unroll
            for (int c3 = 0; c3 < 5; ++c3) {
                float kv = ker[a2 * 5 + c3];
                float2 e = tw[(u * (a2 - 2) + v * (c3 - 2)) & 127];
                khr = fmaf(kv, e.x, khr);
                khi = fmaf(kv, e.y, khi);
            }
        }
        const int slot = uu * 16 + v;
        float* FV = ws + FVC_OFF + (size_t)bt * 1024;
        FV[slot * 2]     = s * (mr * khr - mi_ * khi);
        FV[slot * 2 + 1] = s * (mr * khi + mi_ * khr);
    }
}

// ---------------------------------------------------------------------------
// K2: per-(b,q,quarter): zeros, kx column, mix, inverse transform 32 rows.
// grid 512; block 256.
// ---------------------------------------------------------------------------
__global__ __launch_bounds__(256) void dist_mix_inv_kernel(
    const float* __restrict__ ws, float* __restrict__ out)
{
    __shared__ float2 tw[128];
    __shared__ float kxs[32];
    __shared__ float fmP[32 * 36];   // slot(u,v) -> u*36 + v*2 (r,i interleaved)
    __shared__ float Az[32 * 36];    // row l   -> l*36 + v*2 (r,i interleaved)

    const int tid     = threadIdx.x;
    const int b       = blockIdx.x >> 7;
    const int rest    = blockIdx.x & 127;
    const int q       = rest >> 2;
    const int quarter = rest & 3;
    const size_t obase = (size_t)(b * 32 + q) * 32768;

    if (tid < 128) {
        float s, c;
        sincosf((float)tid * TWOPI_128, &s, &c);
        tw[tid] = make_float2(c, s);
    }

    // ---- zeros: top half rows [quarter*32, quarter*32+32) ----
    {
        const float4 z4 = make_float4(0.f, 0.f, 0.f, 0.f);
        #pragma unroll
        for (int k = 0; k < 4; ++k) {
            int idx = k * 256 + tid;
            *(float4*)(out + obase + (size_t)quarter * 4096 + (size_t)idx * 4) = z4;
        }
    }

    // ---- dist: kx[b,t,q] for t=0..31 ----
    {
        const int t = tid >> 3, seg = tid & 7;
        const float4* qp = (const float4*)(ws + PHIQ_OFF + (size_t)(b * 32 + t) * 1024) + seg * 32;
        const float4* kp = (const float4*)(ws + PHIK_OFF + (size_t)(b * 32 + q) * 1024) + seg * 32;
        float acc = 0.f;
        #pragma unroll 8
        for (int d = 0; d < 32; ++d) {
            float4 qv = qp[d], kv = kp[d];
            float d0 = qv.x - kv.x, d1 = qv.y - kv.y;
            float d2 = qv.z - kv.z, d3 = qv.w - kv.w;
            acc = fmaf(d0, d0, acc); acc = fmaf(d1, d1, acc);
            acc = fmaf(d2, d2, acc); acc = fmaf(d3, d3, acc);
        }
        acc += __shfl_xor(acc, 1);
        acc += __shfl_xor(acc, 2);
        acc += __shfl_xor(acc, 4);
        if (seg == 0) {
            float l2  = sqrtf(acc + 1e-8f);
            float kxv = (t == 31) ? 0.f : expf(-l2);
            kxs[t] = kxv;
            if (quarter == 0)
                out[OUT_KX_OFF + (b * 32 + t) * 32 + q] = kxv;
        }
    }
    __syncthreads();

    // ---- mix: fm = sum_t kx[t] * Fvc[b,t] ----
    {
        float4 acc = make_float4(0.f, 0.f, 0.f, 0.f);
        const float4* FV = (const float4*)(ws + FVC_OFF) + (size_t)b * 32 * 256;
        for (int i = 0; i < 31; ++i) {
            float kv = kxs[i];
            float4 f = FV[(size_t)i * 256 + tid];
            acc.x = fmaf(kv, f.x, acc.x);
            acc.y = fmaf(kv, f.y, acc.y);
            acc.z = fmaf(kv, f.z, acc.z);
            acc.w = fmaf(kv, f.w, acc.w);
        }
        int s0 = tid * 2;
        *(float4*)(fmP + (s0 >> 4) * 36 + (s0 & 15) * 2) = acc;
    }
    __syncthreads();

    // ---- phase 2: A_v(h) for our 32 h rows (rotated twiddles, 2 chains) ----
    {
        const int hl = tid >> 3;
        const int v0 = (tid & 7) * 2;
        const int h  = quarter * 32 + hl;
        const float2 stp = tw[h];
        float cA = 1.f, sA = 0.f;
        const float2 ib = tw[(112 * h) & 127];
        float cB = ib.x, sB = ib.y;
        float ar0 = 0.f, ai0 = 0.f, ar1 = 0.f, ai1 = 0.f;
        #pragma unroll 4
        for (int j = 0; j < 16; ++j) {
            float4 fa = *(const float4*)(fmP + j * 36 + v0 * 2);
            ar0 = fmaf(fa.x, cA, fmaf(-fa.y, sA, ar0));
            ai0 = fmaf(fa.x, sA, fmaf( fa.y, cA, ai0));
            ar1 = fmaf(fa.z, cA, fmaf(-fa.w, sA, ar1));
            ai1 = fmaf(fa.z, sA, fmaf( fa.w, cA, ai1));
            float4 fb = *(const float4*)(fmP + (j + 16) * 36 + v0 * 2);
            ar0 = fmaf(fb.x, cB, fmaf(-fb.y, sB, ar0));
            ai0 = fmaf(fb.x, sB, fmaf( fb.y, cB, ai0));
            ar1 = fmaf(fb.z, cB, fmaf(-fb.w, sB, ar1));
            ai1 = fmaf(fb.z, sB, fmaf( fb.w, cB, ai1));
            float t0 = fmaf(cA, stp.x, -(sA * stp.y));
            float t1 = fmaf(cA, stp.y,  (sA * stp.x));
            cA = t0; sA = t1;
            t0 = fmaf(cB, stp.x, -(sB * stp.y));
            t1 = fmaf(cB, stp.y,  (sB * stp.x));
            cB = t0; sB = t1;
        }
        *(float4*)(Az + hl * 36 + v0 * 2) = make_float4(ar0, ai0, ar1, ai1);
    }

    // per-lane pixel twiddles (w2 = lane; lane+64 via parity trick)
    const int wv   = tid >> 6;
    const int lane = tid & 63;
    float cw[16], sw[16];
    #pragma unroll
    for (int v = 1; v < 16; ++v) {
        float2 t = tw[(v * lane) & 127];
        cw[v] = t.x; sw[v] = t.y;
    }
    __syncthreads();

    // ---- phase 3: 8 rows per wave, 2 pixels per lane per row ----
    for (int lr = 0; lr < 8; ++lr) {
        int l = wv * 8 + lr;
        const float4* az = (const float4*)(Az + l * 36);
        float4 f0 = az[0];
        float base = f0.x;                               // v=0 (real part)
        float accO = f0.z * cw[1] - f0.w * sw[1];        // v=1
        float accE = 0.f;
        #pragma unroll
        for (int t2 = 1; t2 < 8; ++t2) {
            float4 f = az[t2];
            accE = fmaf(f.x, cw[2 * t2],     fmaf(-f.y, sw[2 * t2],     accE));
            accO = fmaf(f.z, cw[2 * t2 + 1], fmaf(-f.w, sw[2 * t2 + 1], accO));
        }
        float pA = base + 2.f * (accE + accO);
        float pB = base + 2.f * (accE - accO);
        int r = quarter * 32 + l;
        out[obase + (size_t)(128 + r) * 128 + lane]      = pA * OUT_SCALE;
        out[obase + (size_t)(128 + r) * 128 + lane + 64] = pB * OUT_SCALE;
    }
}

extern "C" void kernel_launch(void* const* d_in, const int* in_sizes, int n_in,
                              void* d_out, int out_size, void* d_ws, size_t ws_size,
                              hipStream_t stream)
{
    (void)in_sizes; (void)n_in; (void)out_size; (void)ws_size;
    const float* z    = (const float*)d_in[0];
    const float* qw1r = (const float*)d_in[1];
    const float* qw1i = (const float*)d_in[2];
    const float* qw2r = (const float*)d_in[3];
    const float* qw2i = (const float*)d_in[4];
    const float* kw1r = (const float*)d_in[5];
    const float* kw1i = (const float*)d_in[6];
    const float* kw2r = (const float*)d_in[7];
    const float* kw2i = (const float*)d_in[8];
    const float* icl  = (const float*)d_in[9];
    const float* ker  = (const float*)d_in[10];
    float* ws  = (float*)d_ws;
    float* out = (float*)d_out;

    hipLaunchKernelGGL(dft_rows_kernel, dim3(2048), dim3(256), 0, stream, z, out);
    hipLaunchKernelGGL(modes_kernel, dim3(1024), dim3(128), 0, stream,
                       out, qw1r, qw1i, qw2r, qw2i, kw1r, kw1i, kw2r, kw2i,
                       icl, ker, ws);
    hipLaunchKernelGGL(dist_mix_inv_kernel, dim3(512), dim3(256), 0, stream, ws, out);
}